// Round 1
// baseline (217.051 us; speedup 1.0000x reference)
//
#include <hip/hip_runtime.h>

#define B_TOT    1024
#define NUM_VARS 2048
#define LEAVES   (2 * NUM_VARS)          // 4096
#define LEVELS   12
#define WIDTH    4096
#define FANIN    4
#define TOTAL    (LEAVES + LEVELS * WIDTH)   // 53248

// ---------------------------------------------------------------------------
// Leaf materialization with transpose:
//   buf[v][b]            = x[b][v]
//   buf[v + NUM_VARS][b] = 1 - x[b][v]
// buf is node-major with batch contiguous (stride Bc).
// grid: (NUM_VARS/64, Bc/64), block (64,16); LDS 64x65 tile (no bank conflicts).
// ---------------------------------------------------------------------------
__global__ __launch_bounds__(1024) void leaf_kernel(const float* __restrict__ x,
                                                    float* __restrict__ buf,
                                                    int b0, int Bc)
{
    __shared__ float tile[64][65];
    const int v0 = blockIdx.x * 64;
    const int bb = blockIdx.y * 64;

    // Coalesced read: v is the fast dim in x's row-major layout.
    const int tv = threadIdx.x;   // 0..63  -> v offset
    const int tb = threadIdx.y;   // 0..15
    #pragma unroll
    for (int i = 0; i < 4; ++i) {
        const int b_local = tb + i * 16;
        const int b = b0 + bb + b_local;
        tile[tv][b_local] = x[(size_t)b * NUM_VARS + v0 + tv];
    }
    __syncthreads();

    // Coalesced write: batch is the fast dim in buf.
    const int wb = threadIdx.x;   // 0..63 -> batch offset
    #pragma unroll
    for (int i = 0; i < 4; ++i) {
        const int v_local = tb + i * 16;
        const float val = tile[v_local][wb];
        const int v = v0 + v_local;
        buf[(size_t)v * Bc + bb + wb]              = val;
        buf[(size_t)(v + NUM_VARS) * Bc + bb + wb] = 1.0f - val;
    }
}

// ---------------------------------------------------------------------------
// One circuit level. One node per block; threads cover the batch via float4.
// child indices + op are wave-uniform -> scalar loads, no divergence.
// All four child reads are contiguous coalesced rows of Bc floats.
// ---------------------------------------------------------------------------
__global__ __launch_bounds__(256) void level_kernel(const float* __restrict__ buf,
                                                    float* __restrict__ out_base,
                                                    const int4* __restrict__ child,
                                                    const int* __restrict__ op,
                                                    int Bc)
{
    const int w = blockIdx.x;
    const int4 c = child[w];       // uniform per block
    const int  o = op[w];          // uniform per block
    const int  t = threadIdx.x;    // float4 index into batch

    const float4* p0 = (const float4*)(buf + (size_t)c.x * Bc);
    const float4* p1 = (const float4*)(buf + (size_t)c.y * Bc);
    const float4* p2 = (const float4*)(buf + (size_t)c.z * Bc);
    const float4* p3 = (const float4*)(buf + (size_t)c.w * Bc);

    const float4 v0 = p0[t];
    const float4 v1 = p1[t];
    const float4 v2 = p2[t];
    const float4 v3 = p3[t];

    float4 r;
    if (o == 0) {  // AND -> product, left-to-right like np.prod
        r.x = ((v0.x * v1.x) * v2.x) * v3.x;
        r.y = ((v0.y * v1.y) * v2.y) * v3.y;
        r.z = ((v0.z * v1.z) * v2.z) * v3.z;
        r.w = ((v0.w * v1.w) * v2.w) * v3.w;
    } else {       // OR -> sum
        r.x = ((v0.x + v1.x) + v2.x) + v3.x;
        r.y = ((v0.y + v1.y) + v2.y) + v3.y;
        r.z = ((v0.z + v1.z) + v2.z) + v3.z;
        r.w = ((v0.w + v1.w) + v2.w) + v3.w;
    }
    ((float4*)(out_base + (size_t)w * Bc))[t] = r;
}

// ---------------------------------------------------------------------------
// Copy the root node's row (last node, last level) to d_out.
// ---------------------------------------------------------------------------
__global__ void out_kernel(const float* __restrict__ buf, float* __restrict__ out,
                           int b0, int Bc)
{
    const int t = blockIdx.x * blockDim.x + threadIdx.x;
    if (t < Bc) out[b0 + t] = buf[(size_t)(TOTAL - 1) * Bc + t];
}

extern "C" void kernel_launch(void* const* d_in, const int* in_sizes, int n_in,
                              void* d_out, int out_size, void* d_ws, size_t ws_size,
                              hipStream_t stream)
{
    const float* x         = (const float*)d_in[0];
    const int*   child_idx = (const int*)d_in[1];
    const int*   op_type   = (const int*)d_in[2];
    float*       out       = (float*)d_out;
    float*       buf       = (float*)d_ws;

    // Batch chunk so the transposed buffer fits the workspace.
    // Full size: TOTAL * 1024 * 4 = 218 MB.
    int Bc = B_TOT;
    while ((size_t)TOTAL * (size_t)Bc * sizeof(float) > ws_size && Bc > 64) Bc >>= 1;

    for (int b0 = 0; b0 < B_TOT; b0 += Bc) {
        {
            dim3 blk(64, 16);
            dim3 grd(NUM_VARS / 64, Bc / 64);
            leaf_kernel<<<grd, blk, 0, stream>>>(x, buf, b0, Bc);
        }
        for (int l = 0; l < LEVELS; ++l) {
            const int4* child = (const int4*)(child_idx + (size_t)l * WIDTH * FANIN);
            const int*  op    = op_type + (size_t)l * WIDTH;
            float* out_base   = buf + (size_t)(LEAVES + l * WIDTH) * Bc;
            level_kernel<<<WIDTH, Bc / 4, 0, stream>>>(buf, out_base, child, op, Bc);
        }
        out_kernel<<<(Bc + 255) / 256, 256, 0, stream>>>(buf, out, b0, Bc);
    }
}